// Round 5
// baseline (295.265 us; speedup 1.0000x reference)
//
#include <hip/hip_runtime.h>
#include <hip/hip_bf16.h>

#define N_   8192
#define DIM_ 512
#define DK_  128
#define DV_  512
#define L2E_ 1.44269504088896f

typedef short short8 __attribute__((ext_vector_type(8)));
typedef float f32x4  __attribute__((ext_vector_type(4)));

__device__ __forceinline__ float fexp2(float x) { return __builtin_amdgcn_exp2f(x); }

__device__ __forceinline__ ushort f2bf(float f) {
    union { float f; unsigned u; } v; v.f = f;
    unsigned u = v.u;
    return (ushort)((u + 0x7FFFu + ((u >> 16) & 1u)) >> 16);
}
__device__ __forceinline__ float bf2f(ushort u) { return __uint_as_float(((unsigned)u) << 16); }

// ---- kernel 1: u1 = w_w^T a1, u2 = w_w^T a2, c1 = w_b.a1, c2 = w_b.a2 ----
__global__ void prep_kernel(const float* __restrict__ w_w, const float* __restrict__ w_b,
                            const float* __restrict__ a, float* __restrict__ u1,
                            float* __restrict__ u2, float* __restrict__ scal) {
    int d = threadIdx.x;                 // 512 threads
    float s1 = 0.f, s2 = 0.f;
    for (int k = 0; k < DK_; ++k) {
        float w = w_w[k * DIM_ + d];
        s1 += w * a[k];
        s2 += w * a[DK_ + k];
    }
    u1[d] = s1; u2[d] = s2;
    if (d == 0) { float c = 0.f; for (int k = 0; k < DK_; ++k) c += w_b[k] * a[k];        scal[0] = c; }
    if (d == 1) { float c = 0.f; for (int k = 0; k < DK_; ++k) c += w_b[k] * a[DK_ + k];  scal[1] = c; }
}

// ---- kernel 2: e_src[i], e_dst[i], and bf16 copy of x ----
__global__ __launch_bounds__(256) void e_kernel(const float* __restrict__ x,
        const float* __restrict__ u1, const float* __restrict__ u2,
        const float* __restrict__ scal, float* __restrict__ e_src, float* __restrict__ e_dst,
        ushort* __restrict__ xbf) {
    int wid = threadIdx.x >> 6, lane = threadIdx.x & 63;
    int row = blockIdx.x * 4 + wid;
    const float* xr = x + (size_t)row * DIM_;
    int d0 = lane * 8;
    f32x4 xa = *(const f32x4*)(xr + d0);
    f32x4 xb = *(const f32x4*)(xr + d0 + 4);
    f32x4 ua = *(const f32x4*)(u1 + d0);
    f32x4 ub = *(const f32x4*)(u1 + d0 + 4);
    f32x4 va = *(const f32x4*)(u2 + d0);
    f32x4 vb = *(const f32x4*)(u2 + d0 + 4);
    short8 xv;
#pragma unroll
    for (int e = 0; e < 4; ++e) { xv[e] = (short)f2bf(xa[e]); xv[e + 4] = (short)f2bf(xb[e]); }
    *(short8*)(xbf + (size_t)row * DIM_ + d0) = xv;
    float s1 = 0.f, s2 = 0.f;
#pragma unroll
    for (int e = 0; e < 4; ++e) {
        s1 += xa[e] * ua[e] + xb[e] * ub[e];
        s2 += xa[e] * va[e] + xb[e] * vb[e];
    }
    for (int off = 32; off; off >>= 1) { s1 += __shfl_xor(s1, off); s2 += __shfl_xor(s2, off); }
    if (lane == 0) {
        e_src[row] = s1 + scal[0];
        e_dst[row] = s2 + scal[1];
    }
}

// ---- kernel 3: M = max_j e_dst[j] ----
__global__ void max_kernel(const float* __restrict__ e_dst, float* __restrict__ scal) {
    __shared__ float red[256];
    int t = threadIdx.x;
    float m = -1e30f;
    for (int i = t; i < N_; i += 256) m = fmaxf(m, e_dst[i]);
    red[t] = m; __syncthreads();
    for (int s = 128; s; s >>= 1) { if (t < s) red[t] = fmaxf(red[t], red[t + s]); __syncthreads(); }
    if (t == 0) scal[2] = red[0];
}

// ---- kernel 4: bitonic sort of (e_dst, j) ascending; -> ks (sorted keys), perm ----
__global__ __launch_bounds__(1024) void sort_kernel(const float* __restrict__ e_dst,
        float* __restrict__ ks, int* __restrict__ perm) {
    __shared__ unsigned skey[N_];   // 32 KiB
    __shared__ ushort   sidx[N_];   // 16 KiB
    int t = threadIdx.x;
    for (int r = t; r < N_; r += 1024) {
        unsigned u = __float_as_uint(e_dst[r]);
        u ^= (unsigned)(((int)u >> 31)) | 0x80000000u;   // orderable-uint transform
        skey[r] = u;
        sidx[r] = (ushort)r;
    }
    __syncthreads();
    for (int k = 2; k <= N_; k <<= 1) {
        for (int j = k >> 1; j > 0; j >>= 1) {
            for (int idx = t; idx < N_; idx += 1024) {
                int l = idx ^ j;
                if (l > idx) {
                    unsigned a = skey[idx], b = skey[l];
                    bool up = ((idx & k) == 0);
                    if ((a > b) == up) {
                        skey[idx] = b; skey[l] = a;
                        ushort ia = sidx[idx]; sidx[idx] = sidx[l]; sidx[l] = ia;
                    }
                }
            }
            __syncthreads();
        }
    }
    for (int r = t; r < N_; r += 1024) {
        unsigned u = skey[r];
        u ^= (u & 0x80000000u) ? 0x80000000u : 0xFFFFFFFFu;
        ks[r] = __uint_as_float(u);
        perm[r] = (int)sidx[r];
    }
}

// ---- kernel 5: G factors in sorted order ----
__global__ __launch_bounds__(256) void gs_kernel(const float* __restrict__ ks,
        const float* __restrict__ scal, float* __restrict__ Gs1, float* __restrict__ Gs2) {
    int j = blockIdx.x * 256 + threadIdx.x;
    float d = (ks[j] - scal[2]) * L2E_;
    Gs1[j] = fexp2(d);
    Gs2[j] = fexp2(0.01f * d);
}

// ---- kernel 6: V[j][c] = bf16( x[j].wv_w[c] + wv_b[c] ), MFMA (A = x rows, B = wv rows) ----
__global__ __launch_bounds__(256) void v_kernel(const ushort* __restrict__ xbf,
        const float* __restrict__ wv_w, const float* __restrict__ wv_b,
        ushort* __restrict__ V) {
    int wid = threadIdx.x >> 6, lane = threadIdx.x & 63;
    int ln16 = lane & 15, kg = lane >> 4;
    int jb = blockIdx.x * 256 + wid * 64;
    int cb = blockIdx.y * 64;
    f32x4 acc[4][4] = {};
    float bias[4];
#pragma unroll
    for (int ng = 0; ng < 4; ++ng) bias[ng] = wv_b[cb + ng * 16 + ln16];
    for (int k0 = 0; k0 < DIM_; k0 += 32) {
        int kk = k0 + kg * 8;
        short8 afr[4], bfr[4];
#pragma unroll
        for (int mg = 0; mg < 4; ++mg)
            afr[mg] = *(const short8*)(xbf + (size_t)(jb + mg * 16 + ln16) * DIM_ + kk);
#pragma unroll
        for (int ng = 0; ng < 4; ++ng) {
            const float* p = wv_w + (size_t)(cb + ng * 16 + ln16) * DIM_ + kk;
            f32x4 lo = *(const f32x4*)p, hi = *(const f32x4*)(p + 4);
            short8 f;
#pragma unroll
            for (int e = 0; e < 4; ++e) { f[e] = (short)f2bf(lo[e]); f[e + 4] = (short)f2bf(hi[e]); }
            bfr[ng] = f;
        }
#pragma unroll
        for (int mg = 0; mg < 4; ++mg)
#pragma unroll
            for (int ng = 0; ng < 4; ++ng)
                acc[mg][ng] = __builtin_amdgcn_mfma_f32_16x16x32_bf16(afr[mg], bfr[ng], acc[mg][ng], 0, 0, 0);
    }
#pragma unroll
    for (int mg = 0; mg < 4; ++mg)
#pragma unroll
        for (int ng = 0; ng < 4; ++ng)
#pragma unroll
            for (int r = 0; r < 4; ++r) {
                int j = jb + mg * 16 + kg * 4 + r;
                int c = cb + ng * 16 + ln16;
                V[(size_t)j * DV_ + c] = f2bf(acc[mg][ng][r] + bias[ng]);
            }
}

// ---- kernel 7: chunk sums of G1*V, G2*V over sorted order (128 chunks x 64 rows) ----
__global__ __launch_bounds__(256) void p1_kernel(const ushort* __restrict__ V,
        const int* __restrict__ perm, const float* __restrict__ Gs1, const float* __restrict__ Gs2,
        float* __restrict__ C1, float* __restrict__ C2) {
    int ch = blockIdx.x, t = threadIdx.x;
    int c2 = t * 2;
    int k0 = ch * 64;
    float a1 = 0.f, b1 = 0.f, a2 = 0.f, b2 = 0.f;
#pragma unroll 4
    for (int r = 0; r < 64; ++r) {
        int k = k0 + r;
        int j = perm[k];
        float g1 = Gs1[k], g2 = Gs2[k];
        unsigned pv = *(const unsigned*)(V + (size_t)j * DV_ + c2);
        float v0 = bf2f((ushort)(pv & 0xFFFFu));
        float v1 = bf2f((ushort)(pv >> 16));
        a1 += g1 * v0; b1 += g1 * v1;
        a2 += g2 * v0; b2 += g2 * v1;
    }
    C1[ch * 512 + c2] = a1; C1[ch * 512 + c2 + 1] = b1;
    C2[ch * 512 + c2] = a2; C2[ch * 512 + c2 + 1] = b2;
}

// ---- kernel 8: chunk carries (block 0: exclusive prefix of C2; block 1: inclusive suffix of C1) ----
__global__ __launch_bounds__(512) void p2_kernel(const float* __restrict__ C1,
        const float* __restrict__ C2, float* __restrict__ pc2, float* __restrict__ sc1) {
    int c = threadIdx.x;
    if (blockIdx.x == 0) {
        float run = 0.f;
#pragma unroll 4
        for (int ch = 0; ch < 128; ++ch) { pc2[ch * 512 + c] = run; run += C2[ch * 512 + c]; }
        pc2[128 * 512 + c] = run;
    } else {
        float s = 0.f;
        sc1[128 * 512 + c] = 0.f;
#pragma unroll 4
        for (int ch = 127; ch >= 0; --ch) { s += C1[ch * 512 + c]; sc1[ch * 512 + c] = s; }
    }
}

// ---- kernel 9: scalar scans of G (denominator tables), a2=excl prefix G2, s1=incl suffix G1 ----
__global__ __launch_bounds__(256) void zscan_kernel(const float* __restrict__ Gs1,
        const float* __restrict__ Gs2, float* __restrict__ za, float* __restrict__ zs) {
    __shared__ float t1[256], t2[256];
    int t = threadIdx.x;
    int base = t * 32;
    float sum1 = 0.f, sum2 = 0.f;
#pragma unroll 4
    for (int q = 0; q < 32; ++q) { sum1 += Gs1[base + q]; sum2 += Gs2[base + q]; }
    t1[t] = sum1; t2[t] = sum2;
    __syncthreads();
    float off2 = 0.f;
    for (int u = 0; u < t; ++u) off2 += t2[u];
    float off1 = 0.f;
    for (int u = t + 1; u < 256; ++u) off1 += t1[u];
    float run2 = off2;
#pragma unroll 4
    for (int q = 0; q < 32; ++q) { za[base + q] = run2; run2 += Gs2[base + q]; }
    float run1 = off1;
#pragma unroll 4
    for (int q = 31; q >= 0; --q) { run1 += Gs1[base + q]; zs[base + q] = run1; }
    if (t == 255) { za[N_] = off2 + sum2; zs[N_] = 0.f; }
}

// ---- kernel 10: full tables A2[k][c] (excl prefix of G2*V), S1[k][c] (incl suffix of G1*V) ----
__global__ __launch_bounds__(256) void p3_kernel(const ushort* __restrict__ V,
        const int* __restrict__ perm, const float* __restrict__ Gs1, const float* __restrict__ Gs2,
        const float* __restrict__ pc2, const float* __restrict__ sc1,
        float* __restrict__ A2t, float* __restrict__ S1t) {
    int ch = blockIdx.x, t = threadIdx.x;
    int c2 = t * 2;
    int k0 = ch * 64;
    float r2a = pc2[ch * 512 + c2], r2b = pc2[ch * 512 + c2 + 1];
#pragma unroll 4
    for (int r = 0; r < 64; ++r) {
        int k = k0 + r;
        int j = perm[k];
        float g2 = Gs2[k];
        unsigned pv = *(const unsigned*)(V + (size_t)j * DV_ + c2);
        float v0 = bf2f((ushort)(pv & 0xFFFFu));
        float v1 = bf2f((ushort)(pv >> 16));
        A2t[(size_t)k * DV_ + c2]     = r2a;
        A2t[(size_t)k * DV_ + c2 + 1] = r2b;
        r2a += g2 * v0; r2b += g2 * v1;
    }
    float r1a = sc1[(ch + 1) * 512 + c2], r1b = sc1[(ch + 1) * 512 + c2 + 1];
#pragma unroll 4
    for (int r = 63; r >= 0; --r) {
        int k = k0 + r;
        int j = perm[k];
        float g1 = Gs1[k];
        unsigned pv = *(const unsigned*)(V + (size_t)j * DV_ + c2);
        float v0 = bf2f((ushort)(pv & 0xFFFFu));
        float v1 = bf2f((ushort)(pv >> 16));
        r1a += g1 * v0; r1b += g1 * v1;
        S1t[(size_t)k * DV_ + c2]     = r1a;
        S1t[(size_t)k * DV_ + c2 + 1] = r1b;
    }
    if (ch == 127) {
        A2t[(size_t)N_ * DV_ + c2]     = pc2[128 * 512 + c2];
        A2t[(size_t)N_ * DV_ + c2 + 1] = pc2[128 * 512 + c2 + 1];
        S1t[(size_t)N_ * DV_ + c2]     = 0.f;
        S1t[(size_t)N_ * DV_ + c2 + 1] = 0.f;
    }
}

// ---- kernel 11: out[i] = (F2*A2[k_i] + F1*S1[k_i]) / z_i, k_i via binary search ----
__global__ __launch_bounds__(256) void out_kernel(const float* __restrict__ e_src,
        const float* __restrict__ scal, const float* __restrict__ ks,
        const float* __restrict__ za, const float* __restrict__ zs,
        const float* __restrict__ A2t, const float* __restrict__ S1t,
        float* __restrict__ out) {
    __shared__ float kls[N_];   // 32 KiB
    int t = threadIdx.x;
    for (int r = t; r < N_; r += 256) kls[r] = ks[r];
    __syncthreads();
    float M = scal[2];
    int i0 = blockIdx.x * 32;
    for (int q = 0; q < 32; ++q) {
        int i = i0 + q;
        float es = e_src[i];
        float tt = es + M;
        float m = fmaxf(tt, 0.01f * tt);
        float F1 = fexp2((tt - m) * L2E_);
        float F2 = fexp2((0.01f * tt - m) * L2E_);
        float key = -es;
        int lo = 0, hi = N_;
        while (lo < hi) { int mid = (lo + hi) >> 1; if (kls[mid] < key) lo = mid + 1; else hi = mid; }
        float z = F2 * za[lo] + F1 * zs[lo];
        float rz = 1.0f / z;
        const float* pa = A2t + (size_t)lo * DV_;
        const float* ps = S1t + (size_t)lo * DV_;
        int c2 = t * 2;
        float o0 = (F2 * pa[c2]     + F1 * ps[c2])     * rz;
        float o1 = (F2 * pa[c2 + 1] + F1 * ps[c2 + 1]) * rz;
        out[(size_t)i * DV_ + c2]     = o0;
        out[(size_t)i * DV_ + c2 + 1] = o1;
    }
}

extern "C" void kernel_launch(void* const* d_in, const int* in_sizes, int n_in,
                              void* d_out, int out_size, void* d_ws, size_t ws_size,
                              hipStream_t stream) {
    const float* x    = (const float*)d_in[0];
    const float* w_w  = (const float*)d_in[1];
    const float* w_b  = (const float*)d_in[2];
    const float* wv_w = (const float*)d_in[3];
    const float* wv_b = (const float*)d_in[4];
    const float* a    = (const float*)d_in[5];
    float* out = (float*)d_out;
    char* ws = (char*)d_ws;

    ushort* V     = (ushort*)(ws);                       // 8 MiB
    ushort* xbf   = (ushort*)(ws + 8388608);             // 8 MiB
    float*  A2t   = (float*)(ws + 16777216);             // 8193*512*4 = 16,779,264
    float*  S1t   = (float*)(ws + 33556480);             // 16,779,264
    char*   sm    = ws + 50335744;                       // small-array region
    float*  u1    = (float*)(sm);
    float*  u2    = (float*)(sm + 2048);
    float*  e_src = (float*)(sm + 4096);
    float*  e_dst = (float*)(sm + 36864);
    float*  scal  = (float*)(sm + 69632);
    float*  ks    = (float*)(sm + 69888);
    int*    perm  = (int*)  (sm + 102656);
    float*  Gs1   = (float*)(sm + 135424);
    float*  Gs2   = (float*)(sm + 168192);
    float*  za    = (float*)(sm + 200960);               // a2[8193]
    float*  zs    = (float*)(sm + 233984);               // s1[8193]
    float*  C1    = (float*)(sm + 267264);               // 128*512*4
    float*  C2    = (float*)(sm + 529408);
    float*  pc2   = (float*)(sm + 791552);               // 129*512*4
    float*  sc1   = (float*)(sm + 1055744);

    hipLaunchKernelGGL(prep_kernel,  dim3(1),        dim3(512),  0, stream, w_w, w_b, a, u1, u2, scal);
    hipLaunchKernelGGL(e_kernel,     dim3(N_ / 4),   dim3(256),  0, stream, x, u1, u2, scal, e_src, e_dst, xbf);
    hipLaunchKernelGGL(max_kernel,   dim3(1),        dim3(256),  0, stream, e_dst, scal);
    hipLaunchKernelGGL(sort_kernel,  dim3(1),        dim3(1024), 0, stream, e_dst, ks, perm);
    hipLaunchKernelGGL(gs_kernel,    dim3(N_ / 256), dim3(256),  0, stream, ks, scal, Gs1, Gs2);
    hipLaunchKernelGGL(v_kernel,     dim3(32, 8),    dim3(256),  0, stream, xbf, wv_w, wv_b, V);
    hipLaunchKernelGGL(p1_kernel,    dim3(128),      dim3(256),  0, stream, V, perm, Gs1, Gs2, C1, C2);
    hipLaunchKernelGGL(p2_kernel,    dim3(2),        dim3(512),  0, stream, C1, C2, pc2, sc1);
    hipLaunchKernelGGL(zscan_kernel, dim3(1),        dim3(256),  0, stream, Gs1, Gs2, za, zs);
    hipLaunchKernelGGL(p3_kernel,    dim3(128),      dim3(256),  0, stream, V, perm, Gs1, Gs2, pc2, sc1, A2t, S1t);
    hipLaunchKernelGGL(out_kernel,   dim3(N_ / 32),  dim3(256),  0, stream, e_src, scal, ks, za, zs, A2t, S1t, out);
}

// Round 6
// 144.722 us; speedup vs baseline: 2.0402x; 2.0402x over previous
//
#include <hip/hip_runtime.h>
#include <hip/hip_bf16.h>

#define N_   8192
#define DIM_ 512
#define DK_  128
#define DV_  512
#define L2E_ 1.44269504088896f

typedef short short8 __attribute__((ext_vector_type(8)));
typedef float f32x4  __attribute__((ext_vector_type(4)));

__device__ __forceinline__ float fexp2(float x) { return __builtin_amdgcn_exp2f(x); }

__device__ __forceinline__ ushort f2bf(float f) {
    union { float f; unsigned u; } v; v.f = f;
    unsigned u = v.u;
    return (ushort)((u + 0x7FFFu + ((u >> 16) & 1u)) >> 16);
}
__device__ __forceinline__ float bf2f(ushort u) { return __uint_as_float(((unsigned)u) << 16); }

// ---- kernel 1: u1 = w_w^T a1, u2 = w_w^T a2, c1 = w_b.a1, c2 = w_b.a2 ----
__global__ __launch_bounds__(256) void prep_kernel(const float* __restrict__ w_w,
                            const float* __restrict__ w_b,
                            const float* __restrict__ a, float* __restrict__ u1,
                            float* __restrict__ u2, float* __restrict__ scal) {
    int d = blockIdx.x * 256 + threadIdx.x;      // 512 threads over 2 blocks
    float s1 = 0.f, s2 = 0.f;
    for (int k = 0; k < DK_; ++k) {
        float w = w_w[k * DIM_ + d];
        s1 += w * a[k];
        s2 += w * a[DK_ + k];
    }
    u1[d] = s1; u2[d] = s2;
    if (d == 0) { float c = 0.f; for (int k = 0; k < DK_; ++k) c += w_b[k] * a[k];        scal[0] = c; }
    if (d == 1) { float c = 0.f; for (int k = 0; k < DK_; ++k) c += w_b[k] * a[DK_ + k];  scal[1] = c; }
}

// ---- kernel 2: e_src[i], e_dst[i], bf16 copy of x, zero rank/ki ----
__global__ __launch_bounds__(256) void e_kernel(const float* __restrict__ x,
        const float* __restrict__ u1, const float* __restrict__ u2,
        const float* __restrict__ scal, float* __restrict__ e_src, float* __restrict__ e_dst,
        ushort* __restrict__ xbf, int* __restrict__ rank, int* __restrict__ ki) {
    int wid = threadIdx.x >> 6, lane = threadIdx.x & 63;
    int row = blockIdx.x * 4 + wid;
    const float* xr = x + (size_t)row * DIM_;
    int d0 = lane * 8;
    f32x4 xa = *(const f32x4*)(xr + d0);
    f32x4 xb = *(const f32x4*)(xr + d0 + 4);
    f32x4 ua = *(const f32x4*)(u1 + d0);
    f32x4 ub = *(const f32x4*)(u1 + d0 + 4);
    f32x4 va = *(const f32x4*)(u2 + d0);
    f32x4 vb = *(const f32x4*)(u2 + d0 + 4);
    short8 xv;
#pragma unroll
    for (int e = 0; e < 4; ++e) { xv[e] = (short)f2bf(xa[e]); xv[e + 4] = (short)f2bf(xb[e]); }
    *(short8*)(xbf + (size_t)row * DIM_ + d0) = xv;
    float s1 = 0.f, s2 = 0.f;
#pragma unroll
    for (int e = 0; e < 4; ++e) {
        s1 += xa[e] * ua[e] + xb[e] * ub[e];
        s2 += xa[e] * va[e] + xb[e] * vb[e];
    }
    for (int off = 32; off; off >>= 1) { s1 += __shfl_xor(s1, off); s2 += __shfl_xor(s2, off); }
    if (lane == 0) {
        e_src[row] = s1 + scal[0];
        e_dst[row] = s2 + scal[1];
    }
    if (lane == 1) rank[row] = 0;
    if (lane == 2) ki[row] = 0;
}

// ---- kernel 3: M = max_j e_dst[j] ----
__global__ void max_kernel(const float* __restrict__ e_dst, float* __restrict__ scal) {
    __shared__ float red[256];
    int t = threadIdx.x;
    float m = -1e30f;
    for (int i = t; i < N_; i += 256) m = fmaxf(m, e_dst[i]);
    red[t] = m; __syncthreads();
    for (int s = 128; s; s >>= 1) { if (t < s) red[t] = fmaxf(red[t], red[t + s]); __syncthreads(); }
    if (t == 0) scal[2] = red[0];
}

// ---- kernel 4: counting-rank. rank[j] = #{j' : e_dst[j'] < e_dst[j] (tie: j'<j)};
//                ki[i] = #{j : e_dst[j] < -e_src[i]}.  grid (32 groups, 16 r-chunks) ----
__global__ __launch_bounds__(256) void rank_kernel(const float* __restrict__ e_dst,
        const float* __restrict__ e_src, int* __restrict__ rank, int* __restrict__ ki) {
    __shared__ float ed[512];
    int t = threadIdx.x;
    int rbase = blockIdx.y * 512;
    for (int q = t; q < 512; q += 256) ed[q] = e_dst[rbase + q];
    __syncthreads();
    int j = blockIdx.x * 256 + t;
    float kj = e_dst[j];
    float kei = -e_src[j];
    int cj = 0, ci = 0;
#pragma unroll 8
    for (int q = 0; q < 512; ++q) {
        float v = ed[q];
        int r = rbase + q;
        cj += (v < kj) || (v == kj && r < j);
        ci += (v < kei);
    }
    atomicAdd(rank + j, cj);
    atomicAdd(ki + j, ci);
}

// ---- kernel 5: scatter perm + G factors in sorted order ----
__global__ __launch_bounds__(256) void scatter_kernel(const float* __restrict__ e_dst,
        const int* __restrict__ rank, const float* __restrict__ scal,
        int* __restrict__ perm, float* __restrict__ Gs1, float* __restrict__ Gs2) {
    int j = blockIdx.x * 256 + threadIdx.x;
    int rk = rank[j];
    float ev = e_dst[j];
    float d = (ev - scal[2]) * L2E_;
    perm[rk] = j;
    Gs1[rk] = fexp2(d);
    Gs2[rk] = fexp2(0.01f * d);
}

// ---- kernel 6: V[j][c] = bf16( x[j].wv_w[c] + wv_b[c] ), MFMA ----
__global__ __launch_bounds__(256) void v_kernel(const ushort* __restrict__ xbf,
        const float* __restrict__ wv_w, const float* __restrict__ wv_b,
        ushort* __restrict__ V) {
    int wid = threadIdx.x >> 6, lane = threadIdx.x & 63;
    int ln16 = lane & 15, kg = lane >> 4;
    int jb = blockIdx.x * 256 + wid * 64;
    int cb = blockIdx.y * 64;
    f32x4 acc[4][4] = {};
    float bias[4];
#pragma unroll
    for (int ng = 0; ng < 4; ++ng) bias[ng] = wv_b[cb + ng * 16 + ln16];
    for (int k0 = 0; k0 < DIM_; k0 += 32) {
        int kk = k0 + kg * 8;
        short8 afr[4], bfr[4];
#pragma unroll
        for (int mg = 0; mg < 4; ++mg)
            afr[mg] = *(const short8*)(xbf + (size_t)(jb + mg * 16 + ln16) * DIM_ + kk);
#pragma unroll
        for (int ng = 0; ng < 4; ++ng) {
            const float* p = wv_w + (size_t)(cb + ng * 16 + ln16) * DIM_ + kk;
            f32x4 lo = *(const f32x4*)p, hi = *(const f32x4*)(p + 4);
            short8 f;
#pragma unroll
            for (int e = 0; e < 4; ++e) { f[e] = (short)f2bf(lo[e]); f[e + 4] = (short)f2bf(hi[e]); }
            bfr[ng] = f;
        }
#pragma unroll
        for (int mg = 0; mg < 4; ++mg)
#pragma unroll
            for (int ng = 0; ng < 4; ++ng)
                acc[mg][ng] = __builtin_amdgcn_mfma_f32_16x16x32_bf16(afr[mg], bfr[ng], acc[mg][ng], 0, 0, 0);
    }
#pragma unroll
    for (int mg = 0; mg < 4; ++mg)
#pragma unroll
        for (int ng = 0; ng < 4; ++ng)
#pragma unroll
            for (int r = 0; r < 4; ++r) {
                int j = jb + mg * 16 + kg * 4 + r;
                int c = cb + ng * 16 + ln16;
                V[(size_t)j * DV_ + c] = f2bf(acc[mg][ng][r] + bias[ng]);
            }
}

// ---- kernel 7: chunk sums of G1*V, G2*V over sorted order (128 chunks x 64 rows) ----
__global__ __launch_bounds__(256) void p1_kernel(const ushort* __restrict__ V,
        const int* __restrict__ perm, const float* __restrict__ Gs1, const float* __restrict__ Gs2,
        float* __restrict__ C1, float* __restrict__ C2) {
    int ch = blockIdx.x, t = threadIdx.x;
    int c2 = t * 2;
    int k0 = ch * 64;
    float a1 = 0.f, b1 = 0.f, a2 = 0.f, b2 = 0.f;
#pragma unroll 4
    for (int r = 0; r < 64; ++r) {
        int k = k0 + r;
        int j = perm[k];
        float g1 = Gs1[k], g2 = Gs2[k];
        unsigned pv = *(const unsigned*)(V + (size_t)j * DV_ + c2);
        float v0 = bf2f((ushort)(pv & 0xFFFFu));
        float v1 = bf2f((ushort)(pv >> 16));
        a1 += g1 * v0; b1 += g1 * v1;
        a2 += g2 * v0; b2 += g2 * v1;
    }
    C1[ch * 512 + c2] = a1; C1[ch * 512 + c2 + 1] = b1;
    C2[ch * 512 + c2] = a2; C2[ch * 512 + c2 + 1] = b2;
}

// ---- kernel 8: chunk carries (block 0: exclusive prefix of C2; block 1: inclusive suffix of C1) ----
__global__ __launch_bounds__(512) void p2_kernel(const float* __restrict__ C1,
        const float* __restrict__ C2, float* __restrict__ pc2, float* __restrict__ sc1) {
    int c = threadIdx.x;
    if (blockIdx.x == 0) {
        float run = 0.f;
#pragma unroll 4
        for (int ch = 0; ch < 128; ++ch) { pc2[ch * 512 + c] = run; run += C2[ch * 512 + c]; }
        pc2[128 * 512 + c] = run;
    } else {
        float s = 0.f;
        sc1[128 * 512 + c] = 0.f;
#pragma unroll 4
        for (int ch = 127; ch >= 0; --ch) { s += C1[ch * 512 + c]; sc1[ch * 512 + c] = s; }
    }
}

// ---- kernel 9: scalar scans of G: za=excl prefix G2, zs=incl suffix G1 ----
__global__ __launch_bounds__(256) void zscan_kernel(const float* __restrict__ Gs1,
        const float* __restrict__ Gs2, float* __restrict__ za, float* __restrict__ zs) {
    __shared__ float t1[256], t2[256];
    int t = threadIdx.x;
    int base = t * 32;
    float sum1 = 0.f, sum2 = 0.f;
#pragma unroll 4
    for (int q = 0; q < 32; ++q) { sum1 += Gs1[base + q]; sum2 += Gs2[base + q]; }
    t1[t] = sum1; t2[t] = sum2;
    __syncthreads();
    float off2 = 0.f;
    for (int u = 0; u < t; ++u) off2 += t2[u];
    float off1 = 0.f;
    for (int u = t + 1; u < 256; ++u) off1 += t1[u];
    float run2 = off2;
#pragma unroll 4
    for (int q = 0; q < 32; ++q) { za[base + q] = run2; run2 += Gs2[base + q]; }
    float run1 = off1;
#pragma unroll 4
    for (int q = 31; q >= 0; --q) { run1 += Gs1[base + q]; zs[base + q] = run1; }
    if (t == 255) { za[N_] = off2 + sum2; zs[N_] = 0.f; }
}

// ---- kernel 10: full tables A2t[k][c] (excl prefix of G2*V), S1t[k][c] (incl suffix of G1*V) ----
__global__ __launch_bounds__(256) void p3_kernel(const ushort* __restrict__ V,
        const int* __restrict__ perm, const float* __restrict__ Gs1, const float* __restrict__ Gs2,
        const float* __restrict__ pc2, const float* __restrict__ sc1,
        float* __restrict__ A2t, float* __restrict__ S1t) {
    int ch = blockIdx.x, t = threadIdx.x;
    int c2 = t * 2;
    int k0 = ch * 64;
    float r2a = pc2[ch * 512 + c2], r2b = pc2[ch * 512 + c2 + 1];
#pragma unroll 4
    for (int r = 0; r < 64; ++r) {
        int k = k0 + r;
        int j = perm[k];
        float g2 = Gs2[k];
        unsigned pv = *(const unsigned*)(V + (size_t)j * DV_ + c2);
        float v0 = bf2f((ushort)(pv & 0xFFFFu));
        float v1 = bf2f((ushort)(pv >> 16));
        A2t[(size_t)k * DV_ + c2]     = r2a;
        A2t[(size_t)k * DV_ + c2 + 1] = r2b;
        r2a += g2 * v0; r2b += g2 * v1;
    }
    float r1a = sc1[(ch + 1) * 512 + c2], r1b = sc1[(ch + 1) * 512 + c2 + 1];
#pragma unroll 4
    for (int r = 63; r >= 0; --r) {
        int k = k0 + r;
        int j = perm[k];
        float g1 = Gs1[k];
        unsigned pv = *(const unsigned*)(V + (size_t)j * DV_ + c2);
        float v0 = bf2f((ushort)(pv & 0xFFFFu));
        float v1 = bf2f((ushort)(pv >> 16));
        r1a += g1 * v0; r1b += g1 * v1;
        S1t[(size_t)k * DV_ + c2]     = r1a;
        S1t[(size_t)k * DV_ + c2 + 1] = r1b;
    }
    if (ch == 127) {
        A2t[(size_t)N_ * DV_ + c2]     = pc2[128 * 512 + c2];
        A2t[(size_t)N_ * DV_ + c2 + 1] = pc2[128 * 512 + c2 + 1];
        S1t[(size_t)N_ * DV_ + c2]     = 0.f;
        S1t[(size_t)N_ * DV_ + c2 + 1] = 0.f;
    }
}

// ---- kernel 11: out[i] = (F2*A2t[ki] + F1*S1t[ki]) / z_i ----
__global__ __launch_bounds__(256) void out_kernel(const float* __restrict__ e_src,
        const float* __restrict__ scal, const int* __restrict__ ki,
        const float* __restrict__ za, const float* __restrict__ zs,
        const float* __restrict__ A2t, const float* __restrict__ S1t,
        float* __restrict__ out) {
    int t = threadIdx.x;
    float M = scal[2];
    int i0 = blockIdx.x * 32;
    int c2 = t * 2;
    for (int q = 0; q < 32; ++q) {
        int i = i0 + q;
        float es = e_src[i];
        float tt = es + M;
        float m = fmaxf(tt, 0.01f * tt);
        float F1 = fexp2((tt - m) * L2E_);
        float F2 = fexp2((0.01f * tt - m) * L2E_);
        int lo = ki[i];
        float z = F2 * za[lo] + F1 * zs[lo];
        float rz = 1.0f / z;
        const float* pa = A2t + (size_t)lo * DV_;
        const float* ps = S1t + (size_t)lo * DV_;
        float o0 = (F2 * pa[c2]     + F1 * ps[c2])     * rz;
        float o1 = (F2 * pa[c2 + 1] + F1 * ps[c2 + 1]) * rz;
        out[(size_t)i * DV_ + c2]     = o0;
        out[(size_t)i * DV_ + c2 + 1] = o1;
    }
}

extern "C" void kernel_launch(void* const* d_in, const int* in_sizes, int n_in,
                              void* d_out, int out_size, void* d_ws, size_t ws_size,
                              hipStream_t stream) {
    const float* x    = (const float*)d_in[0];
    const float* w_w  = (const float*)d_in[1];
    const float* w_b  = (const float*)d_in[2];
    const float* wv_w = (const float*)d_in[3];
    const float* wv_b = (const float*)d_in[4];
    const float* a    = (const float*)d_in[5];
    float* out = (float*)d_out;
    char* ws = (char*)d_ws;

    ushort* V     = (ushort*)(ws);                       // 8 MiB
    ushort* xbf   = (ushort*)(ws + 8388608);             // 8 MiB
    float*  A2t   = (float*)(ws + 16777216);             // 8193*512*4 = 16,779,264
    float*  S1t   = (float*)(ws + 33556480);             // 16,779,264
    char*   sm    = ws + 50335744;                       // small-array region
    float*  u1    = (float*)(sm);
    float*  u2    = (float*)(sm + 2048);
    float*  e_src = (float*)(sm + 4096);
    float*  e_dst = (float*)(sm + 36864);
    float*  scal  = (float*)(sm + 69632);
    float*  Gs1   = (float*)(sm + 69888);
    float*  Gs2   = (float*)(sm + 102656);
    float*  za    = (float*)(sm + 135424);               // 8193 floats (pad 33024)
    float*  zs    = (float*)(sm + 168448);
    float*  C1    = (float*)(sm + 201472);               // 128*512*4 = 262144
    float*  C2    = (float*)(sm + 463616);
    float*  pc2   = (float*)(sm + 725760);               // 129*512*4 = 264192
    float*  sc1   = (float*)(sm + 989952);
    int*    perm  = (int*)  (sm + 1254144);              // 32 KiB
    int*    rank  = (int*)  (sm + 1286912);
    int*    ki    = (int*)  (sm + 1319680);

    hipLaunchKernelGGL(prep_kernel,    dim3(2),          dim3(256), 0, stream, w_w, w_b, a, u1, u2, scal);
    hipLaunchKernelGGL(e_kernel,       dim3(N_ / 4),     dim3(256), 0, stream, x, u1, u2, scal, e_src, e_dst, xbf, rank, ki);
    hipLaunchKernelGGL(max_kernel,     dim3(1),          dim3(256), 0, stream, e_dst, scal);
    hipLaunchKernelGGL(rank_kernel,    dim3(32, 16),     dim3(256), 0, stream, e_dst, e_src, rank, ki);
    hipLaunchKernelGGL(scatter_kernel, dim3(32),         dim3(256), 0, stream, e_dst, rank, scal, perm, Gs1, Gs2);
    hipLaunchKernelGGL(v_kernel,       dim3(32, 8),      dim3(256), 0, stream, xbf, wv_w, wv_b, V);
    hipLaunchKernelGGL(p1_kernel,      dim3(128),        dim3(256), 0, stream, V, perm, Gs1, Gs2, C1, C2);
    hipLaunchKernelGGL(p2_kernel,      dim3(2),          dim3(512), 0, stream, C1, C2, pc2, sc1);
    hipLaunchKernelGGL(zscan_kernel,   dim3(1),          dim3(256), 0, stream, Gs1, Gs2, za, zs);
    hipLaunchKernelGGL(p3_kernel,      dim3(128),        dim3(256), 0, stream, V, perm, Gs1, Gs2, pc2, sc1, A2t, S1t);
    hipLaunchKernelGGL(out_kernel,     dim3(N_ / 32),    dim3(256), 0, stream, e_src, scal, ki, za, zs, A2t, S1t, out);
}

// Round 7
// 127.358 us; speedup vs baseline: 2.3184x; 1.1363x over previous
//
#include <hip/hip_runtime.h>
#include <hip/hip_bf16.h>

#define N_   8192
#define DIM_ 512
#define DK_  128
#define DV_  512
#define L2E_ 1.44269504088896f

typedef short short8 __attribute__((ext_vector_type(8)));
typedef float f32x4  __attribute__((ext_vector_type(4)));

__device__ __forceinline__ float fexp2(float x) { return __builtin_amdgcn_exp2f(x); }

__device__ __forceinline__ ushort f2bf(float f) {
    union { float f; unsigned u; } v; v.f = f;
    unsigned u = v.u;
    return (ushort)((u + 0x7FFFu + ((u >> 16) & 1u)) >> 16);
}
__device__ __forceinline__ float bf2f(ushort u) { return __uint_as_float(((unsigned)u) << 16); }
__device__ __forceinline__ float decode_max(unsigned u) {
    return __uint_as_float((u & 0x80000000u) ? (u ^ 0x80000000u) : ~u);
}

// ---- kernel 1: u1/u2/c1/c2 (blocks 0-1), zero scal_u, wv_w -> bf16 (blocks 2-129) ----
__global__ __launch_bounds__(256) void prep_kernel(const float* __restrict__ w_w,
                            const float* __restrict__ w_b, const float* __restrict__ a,
                            const float* __restrict__ wv_w,
                            float* __restrict__ u1, float* __restrict__ u2,
                            float* __restrict__ scal, ushort* __restrict__ wvbf) {
    int bid = blockIdx.x, t = threadIdx.x;
    if (bid < 2) {
        int d = bid * 256 + t;
        float s1 = 0.f, s2 = 0.f;
        for (int k = 0; k < DK_; ++k) {
            float w = w_w[k * DIM_ + d];
            s1 += w * a[k];
            s2 += w * a[DK_ + k];
        }
        u1[d] = s1; u2[d] = s2;
        if (d == 0) { float c = 0.f; for (int k = 0; k < DK_; ++k) c += w_b[k] * a[k];        scal[0] = c; }
        if (d == 1) { float c = 0.f; for (int k = 0; k < DK_; ++k) c += w_b[k] * a[DK_ + k];  scal[1] = c; }
        if (d == 2) ((unsigned*)scal)[3] = 0u;
    } else {
        int idx = (bid - 2) * 2048 + t * 8;
        f32x4 lo = *(const f32x4*)(wv_w + idx);
        f32x4 hi = *(const f32x4*)(wv_w + idx + 4);
        short8 f;
#pragma unroll
        for (int e = 0; e < 4; ++e) { f[e] = (short)f2bf(lo[e]); f[e + 4] = (short)f2bf(hi[e]); }
        *(short8*)(wvbf + idx) = f;
    }
}

// ---- kernel 2: e_src[i], e_dst[i], bf16 copy of x, zero rank/ki ----
__global__ __launch_bounds__(256) void e_kernel(const float* __restrict__ x,
        const float* __restrict__ u1, const float* __restrict__ u2,
        const float* __restrict__ scal, float* __restrict__ e_src, float* __restrict__ e_dst,
        ushort* __restrict__ xbf, int* __restrict__ rank, int* __restrict__ ki) {
    int wid = threadIdx.x >> 6, lane = threadIdx.x & 63;
    int row = blockIdx.x * 4 + wid;
    const float* xr = x + (size_t)row * DIM_;
    int d0 = lane * 8;
    f32x4 xa = *(const f32x4*)(xr + d0);
    f32x4 xb = *(const f32x4*)(xr + d0 + 4);
    f32x4 ua = *(const f32x4*)(u1 + d0);
    f32x4 ub = *(const f32x4*)(u1 + d0 + 4);
    f32x4 va = *(const f32x4*)(u2 + d0);
    f32x4 vb = *(const f32x4*)(u2 + d0 + 4);
    short8 xv;
#pragma unroll
    for (int e = 0; e < 4; ++e) { xv[e] = (short)f2bf(xa[e]); xv[e + 4] = (short)f2bf(xb[e]); }
    *(short8*)(xbf + (size_t)row * DIM_ + d0) = xv;
    float s1 = 0.f, s2 = 0.f;
#pragma unroll
    for (int e = 0; e < 4; ++e) {
        s1 += xa[e] * ua[e] + xb[e] * ub[e];
        s2 += xa[e] * va[e] + xb[e] * vb[e];
    }
    for (int off = 32; off; off >>= 1) { s1 += __shfl_xor(s1, off); s2 += __shfl_xor(s2, off); }
    if (lane == 0) {
        e_src[row] = s1 + scal[0];
        e_dst[row] = s2 + scal[1];
    }
    if (lane == 1) rank[row] = 0;
    if (lane == 2) ki[row] = 0;
}

// ---- kernel 3: counting-rank + global max of e_dst (x==0 blocks) ----
__global__ __launch_bounds__(256) void rank_kernel(const float* __restrict__ e_dst,
        const float* __restrict__ e_src, int* __restrict__ rank, int* __restrict__ ki,
        float* __restrict__ scal) {
    __shared__ float ed[512];
    __shared__ float red[4];
    int t = threadIdx.x;
    int rbase = blockIdx.y * 512;
    for (int q = t; q < 512; q += 256) ed[q] = e_dst[rbase + q];
    __syncthreads();
    if (blockIdx.x == 0) {      // per-chunk max -> atomicMax (16 atomics total)
        float m = fmaxf(ed[t], ed[t + 256]);
        for (int off = 32; off; off >>= 1) m = fmaxf(m, __shfl_xor(m, off));
        if ((t & 63) == 0) red[t >> 6] = m;
        __syncthreads();
        if (t == 0) {
            m = fmaxf(fmaxf(red[0], red[1]), fmaxf(red[2], red[3]));
            unsigned u = __float_as_uint(m);
            u ^= (unsigned)(((int)u >> 31)) | 0x80000000u;
            atomicMax(((unsigned*)scal) + 3, u);
        }
    }
    int j = blockIdx.x * 256 + t;
    float kj = e_dst[j];
    float kei = -e_src[j];
    int cj = 0, ci = 0;
#pragma unroll 8
    for (int q = 0; q < 512; ++q) {
        float v = ed[q];
        int r = rbase + q;
        cj += (v < kj) || (v == kj && r < j);
        ci += (v < kei);
    }
    atomicAdd(rank + j, cj);
    atomicAdd(ki + j, ci);
}

// ---- kernel 4: scatter perm + G factors in sorted order ----
__global__ __launch_bounds__(256) void scatter_kernel(const float* __restrict__ e_dst,
        const int* __restrict__ rank, const float* __restrict__ scal,
        int* __restrict__ perm, float* __restrict__ Gs1, float* __restrict__ Gs2) {
    int j = blockIdx.x * 256 + threadIdx.x;
    float M = decode_max(((const unsigned*)scal)[3]);
    int rk = rank[j];
    float d = (e_dst[j] - M) * L2E_;
    perm[rk] = j;
    Gs1[rk] = fexp2(d);
    Gs2[rk] = fexp2(0.01f * d);
}

// ---- kernel 5: V[j][c] = bf16( x[j].wv_w[c] + wv_b[c] ), MFMA, both operands bf16 ----
__global__ __launch_bounds__(256) void v_kernel(const ushort* __restrict__ xbf,
        const ushort* __restrict__ wvbf, const float* __restrict__ wv_b,
        ushort* __restrict__ V) {
    int wid = threadIdx.x >> 6, lane = threadIdx.x & 63;
    int ln16 = lane & 15, kg = lane >> 4;
    int jb = blockIdx.x * 256 + wid * 64;
    int cb = blockIdx.y * 64;
    f32x4 acc[4][4] = {};
    float bias[4];
#pragma unroll
    for (int ng = 0; ng < 4; ++ng) bias[ng] = wv_b[cb + ng * 16 + ln16];
    for (int k0 = 0; k0 < DIM_; k0 += 32) {
        int kk = k0 + kg * 8;
        short8 afr[4], bfr[4];
#pragma unroll
        for (int mg = 0; mg < 4; ++mg)
            afr[mg] = *(const short8*)(xbf + (size_t)(jb + mg * 16 + ln16) * DIM_ + kk);
#pragma unroll
        for (int ng = 0; ng < 4; ++ng)
            bfr[ng] = *(const short8*)(wvbf + (size_t)(cb + ng * 16 + ln16) * DIM_ + kk);
#pragma unroll
        for (int mg = 0; mg < 4; ++mg)
#pragma unroll
            for (int ng = 0; ng < 4; ++ng)
                acc[mg][ng] = __builtin_amdgcn_mfma_f32_16x16x32_bf16(afr[mg], bfr[ng], acc[mg][ng], 0, 0, 0);
    }
#pragma unroll
    for (int mg = 0; mg < 4; ++mg)
#pragma unroll
        for (int ng = 0; ng < 4; ++ng)
#pragma unroll
            for (int r = 0; r < 4; ++r) {
                int j = jb + mg * 16 + kg * 4 + r;
                int c = cb + ng * 16 + ln16;
                V[(size_t)j * DV_ + c] = f2bf(acc[mg][ng][r] + bias[ng]);
            }
}

// ---- kernel 6: chunk sums (V-weighted and plain) over sorted order; grid 128ch x 2half ----
__global__ __launch_bounds__(256) void p1_kernel(const ushort* __restrict__ V,
        const int* __restrict__ perm, const float* __restrict__ Gs1, const float* __restrict__ Gs2,
        float* __restrict__ C1, float* __restrict__ C2,
        float* __restrict__ C1z, float* __restrict__ C2z) {
    int ch = blockIdx.x >> 1, half = blockIdx.x & 1;
    int c = half * 256 + threadIdx.x;
    int k0 = ch * 64;
    float a1 = 0.f, a2 = 0.f, z1 = 0.f, z2 = 0.f;
#pragma unroll 4
    for (int r = 0; r < 64; ++r) {
        int k = k0 + r;
        int j = perm[k];
        float g1 = Gs1[k], g2 = Gs2[k];
        float v = bf2f(V[(size_t)j * DV_ + c]);
        a1 += g1 * v; a2 += g2 * v;
        z1 += g1; z2 += g2;
    }
    C1[ch * 512 + c] = a1; C2[ch * 512 + c] = a2;
    if (half == 0 && threadIdx.x == 0) { C1z[ch] = z1; C2z[ch] = z2; }
}

// ---- kernel 7: chunk carries. blocks 0-1: prefix C2 (+z by b0); 2-3: suffix C1 (+z by b2) ----
__global__ __launch_bounds__(256) void p2_kernel(const float* __restrict__ C1,
        const float* __restrict__ C2, const float* __restrict__ C1z, const float* __restrict__ C2z,
        float* __restrict__ pc2, float* __restrict__ sc1,
        float* __restrict__ pz2, float* __restrict__ sz1) {
    __shared__ float zb[128];
    int t = threadIdx.x, b = blockIdx.x;
    int c = (b & 1) * 256 + t;
    if ((b == 0 || b == 2) && t < 128) zb[t] = (b == 0) ? C2z[t] : C1z[t];
    __syncthreads();
    if (b < 2) {
        float run = 0.f;
#pragma unroll 4
        for (int ch = 0; ch < 128; ++ch) { pc2[ch * 512 + c] = run; run += C2[ch * 512 + c]; }
        pc2[128 * 512 + c] = run;
        if (b == 0 && t == 0) {
            float rz = 0.f;
            for (int ch = 0; ch < 128; ++ch) { pz2[ch] = rz; rz += zb[ch]; }
            pz2[128] = rz;
        }
    } else {
        float s = 0.f;
        sc1[128 * 512 + c] = 0.f;
#pragma unroll 4
        for (int ch = 127; ch >= 0; --ch) { s += C1[ch * 512 + c]; sc1[ch * 512 + c] = s; }
        if (b == 2 && t == 0) {
            float sz = 0.f; sz1[128] = 0.f;
            for (int ch = 127; ch >= 0; --ch) { sz += zb[ch]; sz1[ch] = sz; }
        }
    }
}

// ---- kernel 8: full tables A2t (excl prefix G2*V), S1t (incl suffix G1*V), za/zs ----
__global__ __launch_bounds__(256) void p3_kernel(const ushort* __restrict__ V,
        const int* __restrict__ perm, const float* __restrict__ Gs1, const float* __restrict__ Gs2,
        const float* __restrict__ pc2, const float* __restrict__ sc1,
        const float* __restrict__ pz2, const float* __restrict__ sz1,
        float* __restrict__ A2t, float* __restrict__ S1t,
        float* __restrict__ za, float* __restrict__ zs) {
    int ch = blockIdx.x >> 1, half = blockIdx.x & 1;
    int t = threadIdx.x;
    int c = half * 256 + t;
    int k0 = ch * 64;
    bool zown = (half == 0 && t == 0);
    float r2 = pc2[ch * 512 + c];
    float r2z = pz2[ch];
#pragma unroll 4
    for (int r = 0; r < 64; ++r) {
        int k = k0 + r;
        int j = perm[k];
        float g2 = Gs2[k];
        A2t[(size_t)k * DV_ + c] = r2;
        if (zown) za[k] = r2z;
        float v = bf2f(V[(size_t)j * DV_ + c]);
        r2 += g2 * v;
        r2z += g2;
    }
    float r1 = sc1[(ch + 1) * 512 + c];
    float r1z = sz1[ch + 1];
#pragma unroll 4
    for (int r = 63; r >= 0; --r) {
        int k = k0 + r;
        int j = perm[k];
        float g1 = Gs1[k];
        float v = bf2f(V[(size_t)j * DV_ + c]);
        r1 += g1 * v;
        r1z += g1;
        S1t[(size_t)k * DV_ + c] = r1;
        if (zown) zs[k] = r1z;
    }
    if (ch == 127) {
        A2t[(size_t)N_ * DV_ + c] = pc2[128 * 512 + c];
        S1t[(size_t)N_ * DV_ + c] = 0.f;
        if (zown) { za[N_] = pz2[128]; zs[N_] = 0.f; }
    }
}

// ---- kernel 9: out[i] = (F2*A2t[ki] + F1*S1t[ki]) / z_i ----
__global__ __launch_bounds__(256) void out_kernel(const float* __restrict__ e_src,
        const float* __restrict__ scal, const int* __restrict__ ki,
        const float* __restrict__ za, const float* __restrict__ zs,
        const float* __restrict__ A2t, const float* __restrict__ S1t,
        float* __restrict__ out) {
    int t = threadIdx.x;
    float M = decode_max(((const unsigned*)scal)[3]);
    int i0 = blockIdx.x * 16;
    int c2 = t * 2;
#pragma unroll 2
    for (int q = 0; q < 16; ++q) {
        int i = i0 + q;
        float es = e_src[i];
        float tt = es + M;
        float m = fmaxf(tt, 0.01f * tt);
        float F1 = fexp2((tt - m) * L2E_);
        float F2 = fexp2((0.01f * tt - m) * L2E_);
        int lo = ki[i];
        float z = F2 * za[lo] + F1 * zs[lo];
        float rz = 1.0f / z;
        const float* pa = A2t + (size_t)lo * DV_;
        const float* ps = S1t + (size_t)lo * DV_;
        float o0 = (F2 * pa[c2]     + F1 * ps[c2])     * rz;
        float o1 = (F2 * pa[c2 + 1] + F1 * ps[c2 + 1]) * rz;
        out[(size_t)i * DV_ + c2]     = o0;
        out[(size_t)i * DV_ + c2 + 1] = o1;
    }
}

extern "C" void kernel_launch(void* const* d_in, const int* in_sizes, int n_in,
                              void* d_out, int out_size, void* d_ws, size_t ws_size,
                              hipStream_t stream) {
    const float* x    = (const float*)d_in[0];
    const float* w_w  = (const float*)d_in[1];
    const float* w_b  = (const float*)d_in[2];
    const float* wv_w = (const float*)d_in[3];
    const float* wv_b = (const float*)d_in[4];
    const float* a    = (const float*)d_in[5];
    float* out = (float*)d_out;
    char* ws = (char*)d_ws;

    ushort* V     = (ushort*)(ws);                       // 8 MiB
    ushort* xbf   = (ushort*)(ws + 8388608);             // 8 MiB
    float*  A2t   = (float*)(ws + 16777216);             // 8193*512*4
    float*  S1t   = (float*)(ws + 33556480);             // 8193*512*4
    char*   sm    = ws + 50335744;
    float*  u1    = (float*)(sm);
    float*  u2    = (float*)(sm + 2048);
    float*  e_src = (float*)(sm + 4096);
    float*  e_dst = (float*)(sm + 36864);
    float*  scal  = (float*)(sm + 69632);                // [0]=c1 [1]=c2 [3]=max (uint)
    float*  Gs1   = (float*)(sm + 69888);
    float*  Gs2   = (float*)(sm + 102656);
    float*  za    = (float*)(sm + 135424);               // 8193 (pad 33024)
    float*  zs    = (float*)(sm + 168448);
    float*  C1    = (float*)(sm + 201472);               // 256 KiB
    float*  C2    = (float*)(sm + 463616);
    float*  pc2   = (float*)(sm + 725760);               // 129*512*4
    float*  sc1   = (float*)(sm + 989952);
    int*    perm  = (int*)  (sm + 1254144);
    int*    rank  = (int*)  (sm + 1286912);
    int*    ki    = (int*)  (sm + 1319680);
    float*  C1z   = (float*)(sm + 1352448);              // 128 f
    float*  C2z   = (float*)(sm + 1352960);
    float*  pz2   = (float*)(sm + 1353472);              // 129 f (pad 1024)
    float*  sz1   = (float*)(sm + 1354496);
    ushort* wvbf  = (ushort*)(sm + 1355776);             // 512 KiB

    hipLaunchKernelGGL(prep_kernel,    dim3(130),      dim3(256), 0, stream, w_w, w_b, a, wv_w, u1, u2, scal, wvbf);
    hipLaunchKernelGGL(e_kernel,       dim3(N_ / 4),   dim3(256), 0, stream, x, u1, u2, scal, e_src, e_dst, xbf, rank, ki);
    hipLaunchKernelGGL(rank_kernel,    dim3(32, 16),   dim3(256), 0, stream, e_dst, e_src, rank, ki, scal);
    hipLaunchKernelGGL(scatter_kernel, dim3(32),       dim3(256), 0, stream, e_dst, rank, scal, perm, Gs1, Gs2);
    hipLaunchKernelGGL(v_kernel,       dim3(32, 8),    dim3(256), 0, stream, xbf, wvbf, wv_b, V);
    hipLaunchKernelGGL(p1_kernel,      dim3(256),      dim3(256), 0, stream, V, perm, Gs1, Gs2, C1, C2, C1z, C2z);
    hipLaunchKernelGGL(p2_kernel,      dim3(4),        dim3(256), 0, stream, C1, C2, C1z, C2z, pc2, sc1, pz2, sz1);
    hipLaunchKernelGGL(p3_kernel,      dim3(256),      dim3(256), 0, stream, V, perm, Gs1, Gs2, pc2, sc1, pz2, sz1, A2t, S1t, za, zs);
    hipLaunchKernelGGL(out_kernel,     dim3(N_ / 16),  dim3(256), 0, stream, e_src, scal, ki, za, zs, A2t, S1t, out);
}